// Round 7
// baseline (207.728 us; speedup 1.0000x reference)
//
#include <hip/hip_runtime.h>
#include <hip/hip_bf16.h>

#define B_ 8
#define N_ 2048
#define D_ 32
#define RCAP 16                        // CSR entries per row (P(row>16) ~ 1e-15)
#define EM1_DIAG 1.7182818284590452f   // e^1 - 1
#define M_   8.0f
#define EM_  2980.9579870417283f       // e^8

typedef __attribute__((ext_vector_type(8))) short short8;
typedef __attribute__((ext_vector_type(4))) float f32x4;

// ---------------------------------------------------------------------------
// Setup: bf16 copies of x,y, half-norms ||r||^2/2, zero the 64K CSR counters.
// ---------------------------------------------------------------------------
__global__ void setup_kernel(const float* __restrict__ x, const float* __restrict__ y,
                             unsigned short* __restrict__ xb, unsigned short* __restrict__ yb,
                             float* __restrict__ NX, float* __restrict__ NY,
                             int* __restrict__ csr_cnt)
{
    int t = blockIdx.x * 256 + threadIdx.x;          // 0..32767
    const float* src = (t < 16384) ? x : y;
    unsigned short* dstb = (t < 16384) ? xb : yb;
    float* dstn = (t < 16384) ? NX : NY;
    int row = (t < 16384) ? t : (t - 16384);
    const float4* p = reinterpret_cast<const float4*>(src + (size_t)row * D_);
    float ss = 0.f;
    float4 v[8];
    #pragma unroll
    for (int k = 0; k < 8; k++) {
        v[k] = p[k];
        ss += v[k].x * v[k].x + v[k].y * v[k].y + v[k].z * v[k].z + v[k].w * v[k].w;
    }
    short8* dst8 = reinterpret_cast<short8*>(dstb + (size_t)row * D_);
    #pragma unroll
    for (int k = 0; k < 4; k++) {
        const float fv[8] = { v[2*k].x, v[2*k].y, v[2*k].z, v[2*k].w,
                              v[2*k+1].x, v[2*k+1].y, v[2*k+1].z, v[2*k+1].w };
        short8 o;
        #pragma unroll
        for (int e = 0; e < 8; e++) {
            __hip_bfloat16 h = __float2bfloat16(fv[e]);
            o[e] = *reinterpret_cast<const short*>(&h);
        }
        dst8[k] = o;
    }
    dstn[row] = ss * 0.5f;
    csr_cnt[2 * t] = 0;                              // 4*8*2048 = 65536 counters
    csr_cnt[2 * t + 1] = 0;
}

// ---------------------------------------------------------------------------
// Pair discovery, two-phase per wave:
//  phase 1 (hot): store/atomic-free scan — load, 4 MFMA, max-tree, fold the
//    wave-uniform __any into a 32-bit mask.  No stores => compiler pipelines
//    the 32 iterations' loads (R5/R6 had an atomic+store in-loop, which
//    serialized every iteration at memory latency: 61-72us for ~4us of work).
//  phase 2 (rare): re-walk surviving steps (reload is L2-hot), emit row-CSR
//    entries (j, e^G - 1) into 4 tables: 0=xx, 1=yy, 2=yx, 3=xy(=yx^T).
// ---------------------------------------------------------------------------
__global__ __launch_bounds__(256) void discover_kernel(
    const unsigned short* __restrict__ xb, const unsigned short* __restrict__ yb,
    const float* __restrict__ NX, const float* __restrict__ NY,
    int* __restrict__ csr_cnt, uint2* __restrict__ csr_ent)
{
    int m = blockIdx.x >> 8;                          // matrix 0=xx 1=yy 2=yx
    int rem = blockIdx.x & 255;
    int batch = rem >> 5;                             // 8 batches
    int rowblk = rem & 31;                            // 32 blocks of 64 rows
    const unsigned short* rd = (m == 0) ? xb : yb;
    const float*          rN = (m == 0) ? NX : NY;
    const unsigned short* cd = (m == 1) ? yb : xb;
    const float*          cN = (m == 1) ? NY : NX;

    const int tid = threadIdx.x, lane = tid & 63, wv = tid >> 6;
    const int r0 = rowblk * 64;
    const size_t rowbase = (size_t)batch * N_ + r0;

    short8 afrag[4];
    f32x4 cinit[4];
    #pragma unroll
    for (int g = 0; g < 4; g++) {
        afrag[g] = *reinterpret_cast<const short8*>(
            rd + (rowbase + g * 16 + (lane & 15)) * D_ + (lane >> 4) * 8);
        float4 nv = *reinterpret_cast<const float4*>(
            rN + rowbase + g * 16 + (lane >> 4) * 4);
        cinit[g][0] = -nv.x; cinit[g][1] = -nv.y; cinit[g][2] = -nv.z; cinit[g][3] = -nv.w;
    }
    const unsigned short* cdB = cd + (size_t)batch * N_ * D_;
    const float* cNB = cN + batch * N_;
    const int c0w = wv * 512;

    // ---- phase 1: branch-free survivor scan --------------------------------
    unsigned mask = 0;
    #pragma unroll 8
    for (int cc = 0; cc < 32; ++cc) {
        int col = c0w + cc * 16 + (lane & 15);
        short8 bfrag = *reinterpret_cast<const short8*>(
            cdB + (size_t)col * D_ + (lane >> 4) * 8);
        float ny = cNB[col];
        f32x4 d[4];
        #pragma unroll
        for (int g = 0; g < 4; g++)
            d[g] = __builtin_amdgcn_mfma_f32_16x16x32_bf16(afrag[g], bfrag, cinit[g], 0, 0, 0);
        float m0 = fmaxf(fmaxf(d[0][0], d[0][1]), fmaxf(d[0][2], d[0][3]));
        float m1 = fmaxf(fmaxf(d[1][0], d[1][1]), fmaxf(d[1][2], d[1][3]));
        float m2 = fmaxf(fmaxf(d[2][0], d[2][1]), fmaxf(d[2][2], d[2][3]));
        float m3 = fmaxf(fmaxf(d[3][0], d[3][1]), fmaxf(d[3][2], d[3][3]));
        float mx = fmaxf(fmaxf(m0, m1), fmaxf(m2, m3));
        mask |= (__any(mx > ny - 10.0f) ? 1u : 0u) << cc;
    }

    // ---- phase 2: emit (rare; ~1-2 surviving steps per wave) ---------------
    auto push = [&](int T, int row, int colv, float em1) {
        size_t base = (size_t)(T * B_ + batch) * N_ + row;
        int idx = atomicAdd(&csr_cnt[base], 1);
        if (idx < RCAP)
            csr_ent[base * RCAP + idx] = make_uint2((unsigned)colv, __float_as_uint(em1));
    };
    while (mask) {
        int cc = __builtin_ctz(mask);
        mask &= mask - 1;
        int col = c0w + cc * 16 + (lane & 15);
        short8 bfrag = *reinterpret_cast<const short8*>(
            cdB + (size_t)col * D_ + (lane >> 4) * 8);
        float ny = cNB[col];
        f32x4 d[4];
        #pragma unroll
        for (int g = 0; g < 4; g++)
            d[g] = __builtin_amdgcn_mfma_f32_16x16x32_bf16(afrag[g], bfrag, cinit[g], 0, 0, 0);
        #pragma unroll
        for (int g = 0; g < 4; g++) {
            #pragma unroll
            for (int r = 0; r < 4; r++) {
                float dist = ny - d[g][r];
                if (dist < 10.0f) {
                    int i = r0 + g * 16 + (lane >> 4) * 4 + r;
                    if (m == 2) {
                        float em1 = __expf(__expf(-fmaxf(dist, 0.f))) - 1.0f;
                        push(2, i, col, em1);
                        push(3, col, i, em1);
                    } else if (i != col) {
                        float em1 = __expf(__expf(-fmaxf(dist, 0.f))) - 1.0f;
                        push(m, i, col, em1);
                    }
                }
            }
        }
    }
}

// depth-3 tree sum of 8 LDS partials
__device__ __forceinline__ float tree8(const float* r) {
    return ((r[0] + r[1]) + (r[2] + r[3])) + ((r[4] + r[5]) + (r[6] + r[7]));
}

// ---------------------------------------------------------------------------
// Whole Sinkhorn loop, one block per batch, GATHER formulation:
//   lse_j(G_ij + c_j) = M + ln( S + diag_i + sum_{j in CSR row i} ev_j*(e^G-1) )
// ONE barrier per stage: phase1 publishes ev (parity-double-buffered) + S
// partials; barrier; phase2 gathers (pure reads) + f-update (own index only).
// Parity reuse 2 stages apart is safe: a thread in stage s+2's phase1 has
// passed barrier_{s+1}, which all threads only reach after finishing
// phase2_s.  21 barriers total (R6: 42 + LDS-atomic scatters).
// ---------------------------------------------------------------------------
__global__ __launch_bounds__(512) void sinkhorn_kernel(
    const float* __restrict__ a_in, const float* __restrict__ b_in,
    const int* __restrict__ csr_cnt, const uint2* __restrict__ csr_ent,
    float* __restrict__ out)
{
    __shared__ float f[4][N_];          // 0=fxx 1=fyx 2=fxy 3=fyy
    __shared__ float ew[2][N_];         // e^{a-M}, e^{b-M}
    __shared__ float evb[2][4][N_];     // [parity][table slot][col]
    __shared__ float red2[2][4][8];
    __shared__ float resacc;

    const int batch = blockIdx.x;
    const int t = threadIdx.x, lane = t & 63, wv = t >> 6;

    // static CSR metadata for this thread's 4 rows x 4 tables
    int cnts[4][4];
    const uint2* ebase[4];
    #pragma unroll
    for (int T = 0; T < 4; T++) {
        size_t bb = (size_t)(T * B_ + batch) * N_;
        ebase[T] = csr_ent + bb * RCAP;
        #pragma unroll
        for (int q = 0; q < 4; q++)
            cnts[T][q] = min(csr_cnt[bb + t + 512 * q], RCAP);
    }
    #pragma unroll
    for (int q = 0; q < 4; q++) {
        int j = t + 512 * q;
        ew[0][j] = __expf(a_in[batch * N_ + j] - M_);
        ew[1][j] = __expf(b_in[batch * N_ + j] - M_);
        f[0][j] = 0.f; f[1][j] = 0.f; f[2][j] = 0.f; f[3][j] = 0.f;
    }
    if (t == 0) resacc = 0.f;
    // no barrier needed: first phase1 touches only own-index f/ew

    auto gath = [&](const uint2* E, int cnt, const float* evbuf) -> float {
        float g = 0.f;
        for (int k = 0; k < cnt; ++k) {
            uint2 e = E[k];
            g += evbuf[e.x] * __uint_as_float(e.y);
        }
        return g;
    };
    auto wred = [&](float& s) {
        #pragma unroll
        for (int off = 1; off < 64; off <<= 1) s += __shfl_xor(s, off, 64);
    };

    // stage A: fxx (xx, c=a+fxx, diag), fyx (yx, c=a+fxy_old), fyy (yy, c=b+fyy, diag)
    auto stageA = [&](int par) {
        float s0 = 0.f, s1 = 0.f, s2 = 0.f;
        float e0q[4], e2q[4], f0o[4], f1o[4], f3o[4];
        #pragma unroll
        for (int q = 0; q < 4; q++) {
            int j = t + 512 * q;
            f0o[q] = f[0][j]; f1o[q] = f[1][j]; float f2v = f[2][j]; f3o[q] = f[3][j];
            float e0 = ew[0][j] * __expf(f0o[q]); evb[par][0][j] = e0; e0q[q] = e0; s0 += e0;
            float e1 = ew[0][j] * __expf(f2v);    evb[par][1][j] = e1;              s1 += e1;
            float e2 = ew[1][j] * __expf(f3o[q]); evb[par][2][j] = e2; e2q[q] = e2; s2 += e2;
        }
        wred(s0); wred(s1); wred(s2);
        if (lane == 0) { red2[par][0][wv] = s0; red2[par][1][wv] = s1; red2[par][2][wv] = s2; }
        __syncthreads();
        float S0 = tree8(red2[par][0]), S1 = tree8(red2[par][1]), S2 = tree8(red2[par][2]);
        #pragma unroll
        for (int q = 0; q < 4; q++) {
            int i = t + 512 * q;
            float g0 = gath(ebase[0] + (size_t)i * RCAP, cnts[0][q], evb[par][0]);
            f[0][i] = 0.5f * f0o[q] - 0.5f * (M_ + __logf(S0 + e0q[q] * EM1_DIAG + g0));
            float g1 = gath(ebase[2] + (size_t)i * RCAP, cnts[2][q], evb[par][1]);
            f[1][i] = 0.5f * f1o[q] - 0.5f * (M_ + __logf(S1 + g1));
            float g2 = gath(ebase[1] + (size_t)i * RCAP, cnts[1][q], evb[par][2]);
            f[3][i] = 0.5f * f3o[q] - 0.5f * (M_ + __logf(S2 + e2q[q] * EM1_DIAG + g2));
        }
    };

    // stage B: fxy (xy = yx^T, c = b + fyx_new)
    auto stageB = [&](int par) {
        float sB = 0.f;
        float f2o[4];
        #pragma unroll
        for (int q = 0; q < 4; q++) {
            int j = t + 512 * q;
            f2o[q] = f[2][j];
            float ee = ew[1][j] * __expf(f[1][j]); evb[par][0][j] = ee; sB += ee;
        }
        wred(sB);
        if (lane == 0) red2[par][0][wv] = sB;
        __syncthreads();
        float S = tree8(red2[par][0]);
        #pragma unroll
        for (int q = 0; q < 4; q++) {
            int i = t + 512 * q;
            float g = gath(ebase[3] + (size_t)i * RCAP, cnts[3][q], evb[par][0]);
            f[2][i] = 0.5f * f2o[q] - 0.5f * (M_ + __logf(S + g));
        }
    };

    int s = 0;
    for (int it = 0; it < 10; ++it) {
        stageA(s & 1); s++;
        stageB(s & 1); s++;
    }

    // stage E: 4 extrapolation LSEs + fused weighted reduce
    {
        int par = s & 1;
        float s0 = 0.f, s1 = 0.f, s2 = 0.f, s3 = 0.f;
        float e0q[4], e3q[4];
        #pragma unroll
        for (int q = 0; q < 4; q++) {
            int j = t + 512 * q;
            float e0 = ew[0][j] * __expf(f[0][j]); evb[par][0][j] = e0; e0q[q] = e0; s0 += e0; // xx
            float e1 = ew[0][j] * __expf(f[2][j]); evb[par][1][j] = e1;              s1 += e1; // yx
            float e2 = ew[1][j] * __expf(f[1][j]); evb[par][2][j] = e2;              s2 += e2; // xy
            float e3 = ew[1][j] * __expf(f[3][j]); evb[par][3][j] = e3; e3q[q] = e3; s3 += e3; // yy
        }
        wred(s0); wred(s1); wred(s2); wred(s3);
        if (lane == 0) { red2[par][0][wv] = s0; red2[par][1][wv] = s1;
                         red2[par][2][wv] = s2; red2[par][3][wv] = s3; }
        __syncthreads();
        float S0 = tree8(red2[par][0]), S1 = tree8(red2[par][1]);
        float S2 = tree8(red2[par][2]), S3 = tree8(red2[par][3]);
        float ctr = 0.f;
        #pragma unroll
        for (int q = 0; q < 4; q++) {
            int i = t + 512 * q;
            float r0 = M_ + __logf(S0 + e0q[q] * EM1_DIAG +
                                   gath(ebase[0] + (size_t)i * RCAP, cnts[0][q], evb[par][0]));
            float r1 = M_ + __logf(S1 + gath(ebase[2] + (size_t)i * RCAP, cnts[2][q], evb[par][1]));
            float r2 = M_ + __logf(S2 + gath(ebase[3] + (size_t)i * RCAP, cnts[3][q], evb[par][2]));
            float r3 = M_ + __logf(S3 + e3q[q] * EM1_DIAG +
                                   gath(ebase[1] + (size_t)i * RCAP, cnts[1][q], evb[par][3]));
            // f = fe_xy - fe_xx = r0 - r2 ;  g = fe_yx - fe_yy = r3 - r1
            ctr += (r0 - r2) * ew[0][i] * EM_ + (r3 - r1) * ew[1][i] * EM_;
        }
        wred(ctr);
        if (lane == 0) atomicAdd(&resacc, ctr);
        __syncthreads();
        if (t == 0) out[batch] = resacc;   // EPSILON = 1
    }
}

// ---------------------------------------------------------------------------
extern "C" void kernel_launch(void* const* d_in, const int* in_sizes, int n_in,
                              void* d_out, int out_size, void* d_ws, size_t ws_size,
                              hipStream_t stream)
{
    const float* x = (const float*)d_in[0];
    const float* a = (const float*)d_in[1];
    const float* y = (const float*)d_in[2];
    const float* b = (const float*)d_in[3];
    float* out = (float*)d_out;

    char* ws = (char*)d_ws;
    size_t o = 0;
    unsigned short* xb = (unsigned short*)(ws + o); o += (size_t)B_ * N_ * D_ * 2;
    unsigned short* yb = (unsigned short*)(ws + o); o += (size_t)B_ * N_ * D_ * 2;
    float* NX = (float*)(ws + o); o += (size_t)B_ * N_ * 4;
    float* NY = (float*)(ws + o); o += (size_t)B_ * N_ * 4;
    int* csr_cnt = (int*)(ws + o); o += (size_t)4 * B_ * N_ * 4;            // 256 KB
    uint2* csr_ent = (uint2*)(ws + o); o += (size_t)4 * B_ * N_ * RCAP * 8; // 8 MB

    setup_kernel<<<128, 256, 0, stream>>>(x, y, xb, yb, NX, NY, csr_cnt);
    discover_kernel<<<3 * 256, 256, 0, stream>>>(xb, yb, NX, NY, csr_cnt, csr_ent);
    sinkhorn_kernel<<<B_, 512, 0, stream>>>(a, b, csr_cnt, csr_ent, out);
}

// Round 8
// 168.260 us; speedup vs baseline: 1.2346x; 1.2346x over previous
//
#include <hip/hip_runtime.h>
#include <hip/hip_bf16.h>

#define B_ 8
#define N_ 2048
#define D_ 32
#define RCAP 16                        // CSR entries per row (P(row>16) ~ 1e-15)
#define EM1_DIAG 1.7182818284590452f   // e^1 - 1
#define M_   8.0f
#define EM_  2980.9579870417283f       // e^8
#define L2E  1.4426950408889634f
#define LN2  0.6931471805599453f
#define MH_  (0.5f * M_ * L2E)         // 0.5*M in base-2 units

typedef __attribute__((ext_vector_type(8))) short short8;
typedef __attribute__((ext_vector_type(4))) float f32x4;

// ---------------------------------------------------------------------------
// Setup: bf16 copies of x,y, half-norms ||r||^2/2, zero the CSR counters.
// ---------------------------------------------------------------------------
__global__ void setup_kernel(const float* __restrict__ x, const float* __restrict__ y,
                             unsigned short* __restrict__ xb, unsigned short* __restrict__ yb,
                             float* __restrict__ NX, float* __restrict__ NY,
                             int* __restrict__ csr_cnt)
{
    int t = blockIdx.x * 256 + threadIdx.x;          // 0..32767
    const float* src = (t < 16384) ? x : y;
    unsigned short* dstb = (t < 16384) ? xb : yb;
    float* dstn = (t < 16384) ? NX : NY;
    int row = (t < 16384) ? t : (t - 16384);
    const float4* p = reinterpret_cast<const float4*>(src + (size_t)row * D_);
    float ss = 0.f;
    float4 v[8];
    #pragma unroll
    for (int k = 0; k < 8; k++) {
        v[k] = p[k];
        ss += v[k].x * v[k].x + v[k].y * v[k].y + v[k].z * v[k].z + v[k].w * v[k].w;
    }
    short8* dst8 = reinterpret_cast<short8*>(dstb + (size_t)row * D_);
    #pragma unroll
    for (int k = 0; k < 4; k++) {
        const float fv[8] = { v[2*k].x, v[2*k].y, v[2*k].z, v[2*k].w,
                              v[2*k+1].x, v[2*k+1].y, v[2*k+1].z, v[2*k+1].w };
        short8 o;
        #pragma unroll
        for (int e = 0; e < 8; e++) {
            __hip_bfloat16 h = __float2bfloat16(fv[e]);
            o[e] = *reinterpret_cast<const short*>(&h);
        }
        dst8[k] = o;
    }
    dstn[row] = ss * 0.5f;
    csr_cnt[2 * t] = 0;                              // 4*8*2048 = 65536 counters
    csr_cnt[2 * t + 1] = 0;
}

// ---------------------------------------------------------------------------
// Pair discovery (two-phase; phase 1 store/atomic-free so loads pipeline).
// Tables: 0=xx, 1=yy, 2=yx, 3=xy(=yx^T); entry = (col, e^{G}-1).
// ---------------------------------------------------------------------------
__global__ __launch_bounds__(256) void discover_kernel(
    const unsigned short* __restrict__ xb, const unsigned short* __restrict__ yb,
    const float* __restrict__ NX, const float* __restrict__ NY,
    int* __restrict__ csr_cnt, uint2* __restrict__ csr_ent)
{
    int m = blockIdx.x >> 8;                          // matrix 0=xx 1=yy 2=yx
    int rem = blockIdx.x & 255;
    int batch = rem >> 5;                             // 8 batches
    int rowblk = rem & 31;                            // 32 blocks of 64 rows
    const unsigned short* rd = (m == 0) ? xb : yb;
    const float*          rN = (m == 0) ? NX : NY;
    const unsigned short* cd = (m == 1) ? yb : xb;
    const float*          cN = (m == 1) ? NY : NX;

    const int tid = threadIdx.x, lane = tid & 63, wv = tid >> 6;
    const int r0 = rowblk * 64;
    const size_t rowbase = (size_t)batch * N_ + r0;

    short8 afrag[4];
    f32x4 cinit[4];
    #pragma unroll
    for (int g = 0; g < 4; g++) {
        afrag[g] = *reinterpret_cast<const short8*>(
            rd + (rowbase + g * 16 + (lane & 15)) * D_ + (lane >> 4) * 8);
        float4 nv = *reinterpret_cast<const float4*>(
            rN + rowbase + g * 16 + (lane >> 4) * 4);
        cinit[g][0] = -nv.x; cinit[g][1] = -nv.y; cinit[g][2] = -nv.z; cinit[g][3] = -nv.w;
    }
    const unsigned short* cdB = cd + (size_t)batch * N_ * D_;
    const float* cNB = cN + batch * N_;
    const int c0w = wv * 512;

    // ---- phase 1: branch-free survivor scan --------------------------------
    unsigned mask = 0;
    #pragma unroll 8
    for (int cc = 0; cc < 32; ++cc) {
        int col = c0w + cc * 16 + (lane & 15);
        short8 bfrag = *reinterpret_cast<const short8*>(
            cdB + (size_t)col * D_ + (lane >> 4) * 8);
        float ny = cNB[col];
        f32x4 d[4];
        #pragma unroll
        for (int g = 0; g < 4; g++)
            d[g] = __builtin_amdgcn_mfma_f32_16x16x32_bf16(afrag[g], bfrag, cinit[g], 0, 0, 0);
        float m0 = fmaxf(fmaxf(d[0][0], d[0][1]), fmaxf(d[0][2], d[0][3]));
        float m1 = fmaxf(fmaxf(d[1][0], d[1][1]), fmaxf(d[1][2], d[1][3]));
        float m2 = fmaxf(fmaxf(d[2][0], d[2][1]), fmaxf(d[2][2], d[2][3]));
        float m3 = fmaxf(fmaxf(d[3][0], d[3][1]), fmaxf(d[3][2], d[3][3]));
        float mx = fmaxf(fmaxf(m0, m1), fmaxf(m2, m3));
        mask |= (__any(mx > ny - 10.0f) ? 1u : 0u) << cc;
    }

    // ---- phase 2: emit (rare; ~1-2 surviving steps per wave) ---------------
    auto push = [&](int T, int row, int colv, float em1) {
        size_t base = (size_t)(T * B_ + batch) * N_ + row;
        int idx = atomicAdd(&csr_cnt[base], 1);
        if (idx < RCAP)
            csr_ent[base * RCAP + idx] = make_uint2((unsigned)colv, __float_as_uint(em1));
    };
    while (mask) {
        int cc = __builtin_ctz(mask);
        mask &= mask - 1;
        int col = c0w + cc * 16 + (lane & 15);
        short8 bfrag = *reinterpret_cast<const short8*>(
            cdB + (size_t)col * D_ + (lane >> 4) * 8);
        float ny = cNB[col];
        f32x4 d[4];
        #pragma unroll
        for (int g = 0; g < 4; g++)
            d[g] = __builtin_amdgcn_mfma_f32_16x16x32_bf16(afrag[g], bfrag, cinit[g], 0, 0, 0);
        #pragma unroll
        for (int g = 0; g < 4; g++) {
            #pragma unroll
            for (int r = 0; r < 4; r++) {
                float dist = ny - d[g][r];
                if (dist < 10.0f) {
                    int i = r0 + g * 16 + (lane >> 4) * 4 + r;
                    if (m == 2) {
                        float em1 = __expf(__expf(-fmaxf(dist, 0.f))) - 1.0f;
                        push(2, i, col, em1);
                        push(3, col, i, em1);
                    } else if (i != col) {
                        float em1 = __expf(__expf(-fmaxf(dist, 0.f))) - 1.0f;
                        push(m, i, col, em1);
                    }
                }
            }
        }
    }
}

// ---------------------------------------------------------------------------
// Whole Sinkhorn loop, one block of 1024 per batch (4 waves/SIMD for latency
// hiding — R7's 512-thread version stalled 77%). Gather formulation, ONE
// barrier per stage (21 total).  All potentials/weights in REGISTERS (base-2):
//   AW = (a-M)*log2e, F = f*log2e;  ev = exp2(AW + F)
//   F' = 0.5*F - (0.5*log2(tot) + 0.5*M*log2e)
// S-sums via per-wave shfl + one ds_add per wave into Sacc[s%3][tbl]
// (triple-buffered; t0 zeroes buffer (s+1)%3 — ordering proven by barriers).
// evb double-buffered by s&1 (stage s+2 reuse fenced by barrier s+1).
// ---------------------------------------------------------------------------
__global__ __launch_bounds__(1024) void sinkhorn_kernel(
    const float* __restrict__ a_in, const float* __restrict__ b_in,
    const int* __restrict__ csr_cnt, const uint2* __restrict__ csr_ent,
    float* __restrict__ out)
{
    __shared__ float evb[2][4][N_];     // 64 KB  [parity][slot][col]
    __shared__ float Sacc[3][4];
    __shared__ float resacc;

    const int batch = blockIdx.x;
    const int t = threadIdx.x, lane = t & 63;

    int cnts[4][2];
    const uint2* ebase[4];
    #pragma unroll
    for (int T = 0; T < 4; T++) {
        size_t bb = (size_t)(T * B_ + batch) * N_;
        ebase[T] = csr_ent + bb * (size_t)RCAP;
        cnts[T][0] = min(csr_cnt[bb + t], RCAP);
        cnts[T][1] = min(csr_cnt[bb + t + 1024], RCAP);
    }
    float AW[2], BW[2];
    float F0[2] = {0.f, 0.f}, F1[2] = {0.f, 0.f}, F2[2] = {0.f, 0.f}, F3[2] = {0.f, 0.f};
    #pragma unroll
    for (int q = 0; q < 2; q++) {
        int j = t + 1024 * q;
        AW[q] = (a_in[batch * N_ + j] - M_) * L2E;
        BW[q] = (b_in[batch * N_ + j] - M_) * L2E;
    }
    if (t < 12) (&Sacc[0][0])[t] = 0.f;
    if (t == 0) resacc = 0.f;
    __syncthreads();

    auto gath = [&](const uint2* E, int cnt, const float* evbuf) -> float {
        float g = 0.f;
        for (int k = 0; k < cnt; ++k) {
            uint2 e = E[k];
            g += evbuf[e.x] * __uint_as_float(e.y);
        }
        return g;
    };
    auto wredadd = [&](float v, float* dst) {
        #pragma unroll
        for (int off = 1; off < 64; off <<= 1) v += __shfl_xor(v, off, 64);
        if (lane == 0) atomicAdd(dst, v);
    };

    // stage A: fxx (T0, slot0, diag), fyx (T2, slot1), fyy (T1, slot2, diag)
    auto stageA = [&](int s) {
        const int p2 = s & 1, p3 = s % 3, p3n = (s + 1) % 3;
        float e0q[2], e2q[2];
        float s0 = 0.f, s1 = 0.f, s2 = 0.f;
        #pragma unroll
        for (int q = 0; q < 2; q++) {
            int j = t + 1024 * q;
            float e0 = __builtin_amdgcn_exp2f(AW[q] + F0[q]); evb[p2][0][j] = e0; e0q[q] = e0; s0 += e0;
            float e1 = __builtin_amdgcn_exp2f(AW[q] + F2[q]); evb[p2][1][j] = e1;              s1 += e1;
            float e2 = __builtin_amdgcn_exp2f(BW[q] + F3[q]); evb[p2][2][j] = e2; e2q[q] = e2; s2 += e2;
        }
        wredadd(s0, &Sacc[p3][0]);
        wredadd(s1, &Sacc[p3][1]);
        wredadd(s2, &Sacc[p3][2]);
        if (t == 0) { Sacc[p3n][0] = 0.f; Sacc[p3n][1] = 0.f; Sacc[p3n][2] = 0.f; Sacc[p3n][3] = 0.f; }
        __syncthreads();
        float S0 = Sacc[p3][0], S1 = Sacc[p3][1], S2 = Sacc[p3][2];
        #pragma unroll
        for (int q = 0; q < 2; q++) {
            int i = t + 1024 * q;
            float g0 = gath(ebase[0] + (size_t)i * RCAP, cnts[0][q], evb[p2][0]);
            float g1 = gath(ebase[2] + (size_t)i * RCAP, cnts[2][q], evb[p2][1]);
            float g2 = gath(ebase[1] + (size_t)i * RCAP, cnts[1][q], evb[p2][2]);
            float lg0 = __builtin_amdgcn_logf(S0 + fmaf(e0q[q], EM1_DIAG, g0));
            float lg1 = __builtin_amdgcn_logf(S1 + g1);
            float lg2 = __builtin_amdgcn_logf(S2 + fmaf(e2q[q], EM1_DIAG, g2));
            F0[q] = fmaf(0.5f, F0[q], -fmaf(0.5f, lg0, MH_));
            F1[q] = fmaf(0.5f, F1[q], -fmaf(0.5f, lg1, MH_));
            F3[q] = fmaf(0.5f, F3[q], -fmaf(0.5f, lg2, MH_));
        }
    };

    // stage B: fxy (T3, cols y, c = b + fyx_new)
    auto stageB = [&](int s) {
        const int p2 = s & 1, p3 = s % 3, p3n = (s + 1) % 3;
        float sB = 0.f;
        #pragma unroll
        for (int q = 0; q < 2; q++) {
            int j = t + 1024 * q;
            float e = __builtin_amdgcn_exp2f(BW[q] + F1[q]); evb[p2][0][j] = e; sB += e;
        }
        wredadd(sB, &Sacc[p3][0]);
        if (t == 0) { Sacc[p3n][0] = 0.f; Sacc[p3n][1] = 0.f; Sacc[p3n][2] = 0.f; Sacc[p3n][3] = 0.f; }
        __syncthreads();
        float S = Sacc[p3][0];
        #pragma unroll
        for (int q = 0; q < 2; q++) {
            int i = t + 1024 * q;
            float g = gath(ebase[3] + (size_t)i * RCAP, cnts[3][q], evb[p2][0]);
            F2[q] = fmaf(0.5f, F2[q], -fmaf(0.5f, __builtin_amdgcn_logf(S + g), MH_));
        }
    };

    int s = 0;
    for (int it = 0; it < 10; ++it) {
        stageA(s); ++s;
        stageB(s); ++s;
    }

    // stage E (s=20): 4 extrapolation LSEs + fused weighted reduce.
    // r = M + LN2*lg;  f*e^a=(r0-r2)e^a, g*e^b=(r3-r1)e^b — M cancels.
    {
        const int p2 = s & 1, p3 = s % 3;
        float e0q[2], e3q[2];
        float s0 = 0.f, s1 = 0.f, s2 = 0.f, s3 = 0.f;
        #pragma unroll
        for (int q = 0; q < 2; q++) {
            int j = t + 1024 * q;
            float e0 = __builtin_amdgcn_exp2f(AW[q] + F0[q]); evb[p2][0][j] = e0; e0q[q] = e0; s0 += e0; // xx
            float e1 = __builtin_amdgcn_exp2f(AW[q] + F2[q]); evb[p2][1][j] = e1;              s1 += e1; // yx
            float e2 = __builtin_amdgcn_exp2f(BW[q] + F1[q]); evb[p2][2][j] = e2;              s2 += e2; // xy
            float e3 = __builtin_amdgcn_exp2f(BW[q] + F3[q]); evb[p2][3][j] = e3; e3q[q] = e3; s3 += e3; // yy
        }
        wredadd(s0, &Sacc[p3][0]);
        wredadd(s1, &Sacc[p3][1]);
        wredadd(s2, &Sacc[p3][2]);
        wredadd(s3, &Sacc[p3][3]);
        __syncthreads();
        float S0 = Sacc[p3][0], S1 = Sacc[p3][1], S2 = Sacc[p3][2], S3 = Sacc[p3][3];
        float ctr = 0.f;
        #pragma unroll
        for (int q = 0; q < 2; q++) {
            int i = t + 1024 * q;
            float lg0 = __builtin_amdgcn_logf(S0 + fmaf(e0q[q], EM1_DIAG,
                            gath(ebase[0] + (size_t)i * RCAP, cnts[0][q], evb[p2][0])));
            float lg1 = __builtin_amdgcn_logf(S1 +
                            gath(ebase[2] + (size_t)i * RCAP, cnts[2][q], evb[p2][1]));
            float lg2 = __builtin_amdgcn_logf(S2 +
                            gath(ebase[3] + (size_t)i * RCAP, cnts[3][q], evb[p2][2]));
            float lg3 = __builtin_amdgcn_logf(S3 + fmaf(e3q[q], EM1_DIAG,
                            gath(ebase[1] + (size_t)i * RCAP, cnts[1][q], evb[p2][3])));
            float ea = __builtin_amdgcn_exp2f(AW[q]);   // e^{a-M}
            float eb = __builtin_amdgcn_exp2f(BW[q]);   // e^{b-M}
            ctr += (lg0 - lg2) * ea + (lg3 - lg1) * eb;
        }
        ctr *= (LN2 * EM_);
        #pragma unroll
        for (int off = 1; off < 64; off <<= 1) ctr += __shfl_xor(ctr, off, 64);
        if (lane == 0) atomicAdd(&resacc, ctr);
        __syncthreads();
        if (t == 0) out[batch] = resacc;   // EPSILON = 1
    }
}

// ---------------------------------------------------------------------------
extern "C" void kernel_launch(void* const* d_in, const int* in_sizes, int n_in,
                              void* d_out, int out_size, void* d_ws, size_t ws_size,
                              hipStream_t stream)
{
    const float* x = (const float*)d_in[0];
    const float* a = (const float*)d_in[1];
    const float* y = (const float*)d_in[2];
    const float* b = (const float*)d_in[3];
    float* out = (float*)d_out;

    char* ws = (char*)d_ws;
    size_t o = 0;
    unsigned short* xb = (unsigned short*)(ws + o); o += (size_t)B_ * N_ * D_ * 2;
    unsigned short* yb = (unsigned short*)(ws + o); o += (size_t)B_ * N_ * D_ * 2;
    float* NX = (float*)(ws + o); o += (size_t)B_ * N_ * 4;
    float* NY = (float*)(ws + o); o += (size_t)B_ * N_ * 4;
    int* csr_cnt = (int*)(ws + o); o += (size_t)4 * B_ * N_ * 4;            // 256 KB
    uint2* csr_ent = (uint2*)(ws + o); o += (size_t)4 * B_ * N_ * RCAP * 8; // 8 MB

    setup_kernel<<<128, 256, 0, stream>>>(x, y, xb, yb, NX, NY, csr_cnt);
    discover_kernel<<<3 * 256, 256, 0, stream>>>(xb, yb, NX, NY, csr_cnt, csr_ent);
    sinkhorn_kernel<<<B_, 1024, 0, stream>>>(a, b, csr_cnt, csr_ent, out);
}